// Round 2
// baseline (12194.611 us; speedup 1.0000x reference)
//
#include <hip/hip_runtime.h>
#include <hip/hip_bf16.h>

#define T_STEPS 800
#define BATCH   32
#define FEAT    161
#define UNITS   1024
#define CLIPV   20.0f

typedef __attribute__((ext_vector_type(8))) short short8;
typedef __attribute__((ext_vector_type(4))) float f32x4;
typedef unsigned short u16;
typedef unsigned int   u32;
typedef unsigned long long u64;

__device__ __forceinline__ float bf16_f(u16 u) {
    return __uint_as_float(((u32)u) << 16);
}
__device__ __forceinline__ u16 bf16_rn(float x) {
    __hip_bfloat16 b = __float2bfloat16(x);
    return *(u16*)&b;
}
__device__ __forceinline__ u64 ld_agent_u64(const u64* p) {
    return __hip_atomic_load(p, __ATOMIC_RELAXED, __HIP_MEMORY_SCOPE_AGENT);
}
__device__ __forceinline__ u32 ld_agent_u32(const u32* p) {
    return __hip_atomic_load(p, __ATOMIC_RELAXED, __HIP_MEMORY_SCOPE_AGENT);
}
__device__ __forceinline__ float ld_agent_f(const float* p) {
    return __hip_atomic_load(p, __ATOMIC_RELAXED, __HIP_MEMORY_SCOPE_AGENT);
}
__device__ __forceinline__ void st_agent_f(float* p, float v) {
    __hip_atomic_store(p, v, __ATOMIC_RELAXED, __HIP_MEMORY_SCOPE_AGENT);
}
__device__ __forceinline__ short8 ld_agent_b16x8(const u16* p) {
    union { u64 q[2]; short8 v; } u;
    u.q[0] = ld_agent_u64((const u64*)p);
    u.q[1] = ld_agent_u64((const u64*)p + 1);
    return u.v;
}

// ---------------------------------------------------------------------------
// zero h triple-buffer (3 x 64 x 1024 fp32) + 1024 per-wave flags
__global__ __launch_bounds__(256) void init_ws(float* hbuf, u32* flags) {
    int gid = blockIdx.x * 256 + threadIdx.x;         // 16384 threads
    for (int i = gid; i < 3 * 64 * UNITS; i += 64 * 256) hbuf[i] = 0.f;
    if (gid < 1024) flags[gid] = 0u;
}

// ---------------------------------------------------------------------------
// Ut splits: U[k][u] fp32 -> Ut1/2/3[u][k] bf16 (hi/mid/lo, 24-bit total)
__global__ __launch_bounds__(256) void u_split_t(const float* __restrict__ U,
                                                 u16* __restrict__ Ut1,
                                                 u16* __restrict__ Ut2,
                                                 u16* __restrict__ Ut3) {
    __shared__ float tile[32][33];
    int bx = blockIdx.x, by = blockIdx.y;
    int lx = threadIdx.x & 31;
    int ly4 = (threadIdx.x >> 5) * 4;
    #pragma unroll
    for (int j = 0; j < 4; ++j)
        tile[ly4 + j][lx] = U[(size_t)(by * 32 + ly4 + j) * UNITS + bx * 32 + lx];
    __syncthreads();
    #pragma unroll
    for (int j = 0; j < 4; ++j) {
        float x = tile[lx][ly4 + j];
        size_t o = (size_t)(bx * 32 + ly4 + j) * UNITS + by * 32 + lx;
        u16 s1 = bf16_rn(x);  float r1 = x - bf16_f(s1);
        u16 s2 = bf16_rn(r1); float r2 = r1 - bf16_f(s2);
        u16 s3 = bf16_rn(r2);
        Ut1[o] = s1; Ut2[o] = s2; Ut3[o] = s3;
    }
}

// ---------------------------------------------------------------------------
__global__ __launch_bounds__(256) void xw_gemm(const float* __restrict__ inp,
                                               const float* __restrict__ W,
                                               const float* __restrict__ bias,
                                               float* __restrict__ xW) {
    __shared__ float xs[8 * FEAT];
    int t = blockIdx.x;
    int b0 = blockIdx.y * 8;
    int tid = threadIdx.x;

    for (int i = tid; i < 8 * FEAT; i += 256) {
        int j = i / FEAT;
        int f = i - j * FEAT;
        xs[i] = inp[((size_t)(b0 + j) * T_STEPS + t) * FEAT + f];
    }
    __syncthreads();

    float bv[4];
    #pragma unroll
    for (int c = 0; c < 4; ++c) bv[c] = bias[tid + c * 256];

    float acc[8][4];
    #pragma unroll
    for (int j = 0; j < 8; ++j)
        #pragma unroll
        for (int c = 0; c < 4; ++c) acc[j][c] = bv[c];

    for (int f = 0; f < FEAT; ++f) {
        float w0 = W[(size_t)f * UNITS + tid];
        float w1 = W[(size_t)f * UNITS + tid + 256];
        float w2 = W[(size_t)f * UNITS + tid + 512];
        float w3 = W[(size_t)f * UNITS + tid + 768];
        #pragma unroll
        for (int j = 0; j < 8; ++j) {
            float xv = xs[j * FEAT + f];
            acc[j][0] += xv * w0;
            acc[j][1] += xv * w1;
            acc[j][2] += xv * w2;
            acc[j][3] += xv * w3;
        }
    }

    #pragma unroll
    for (int j = 0; j < 8; ++j)
        #pragma unroll
        for (int c = 0; c < 4; ++c)
            xW[((size_t)t * BATCH + b0 + j) * UNITS + tid + c * 256] = acc[j][c];
}

// ---------------------------------------------------------------------------
// Dataflow MFMA scan. 128 blocks x 512 threads.
// Block (rg 0..3, ug 0..31): rows [rg*16,+16) (row = dir*32+b), cols [ug*32,+32).
// Wave kq: k-slice [kq*128,+128); sources = blocks (rg, 4kq..4kq+3).
//
// Sync = per-WAVE monotone flags, flags[(rg*32+ug)*8 + w]. Wave w publishes
// flag=t+1 with a RELEASE store (emits per-wave s_waitcnt vmcnt(0)) right
// after its coalesced h(t+1) row stores -> no second block barrier, no
// kq0 serialization. Consumer wave polls the 32 flags of its 4 source
// blocks (128B, one u64/lane/iter) until all >= t.
//
// WAR with THREE h buffers (store t+1 overwrites t-2): flag(t) from any
// source wave implies that block's single per-step __syncthreads passed,
// i.e. ALL its 8 waves' polls of flags(t-1) succeeded; those polls jointly
// cover every block of the rg group, and each flag(t-1) was itself
// published after that block's barrier drained its state-(t-2) loads
// (per-wave vmcnt(0) at the barrier). So all t-2 readers are done before
// any t+1 store. Max skew is 1 step, so "flag >= t" cannot alias a
// 3-buffer slot.
__global__ __launch_bounds__(512) void rnn_scan(
        const float* __restrict__ xW,
        const u16* __restrict__ Ut1, const u16* __restrict__ Ut2,
        const u16* __restrict__ Ut3,
        float* __restrict__ hbuf, u32* __restrict__ flags,
        float* __restrict__ out) {
    // partials padded to stride 5 (coprime with 32 banks -> <=2-way, free)
    __shared__ float redf[2][8][2][64][5];   // 40 KB, double-buffered

    const int tid  = threadIdx.x;
    const int bk   = blockIdx.x;
    const int lane = tid & 63;
    const int kq   = tid >> 6;       // 0..7 (wave id)
    const int quad = lane >> 4;      // 0..3
    const int n16  = lane & 15;
    const int rg   = bk & 3;
    const int ug   = bk >> 2;
    const int R0   = rg * 16;
    const int u0   = ug * 32;
    const int dir  = rg >> 1;

    // output-element ownership (1 elem/lane): row R0+er, col u0+ec
    const int er  = tid >> 5;                      // 0..15 (wave kq owns er=2kq,2kq+1)
    const int ec  = tid & 31;                      // 0..31
    const int enq = ec >> 4;
    const int ele = ((er >> 2) << 4) + (ec & 15);  // source lane in redf
    const int eje = er & 3;                        // f32x4 element
    const int eb  = (R0 + er) & 31;                // batch row for xW
    const size_t hoff = (size_t)(R0 + er) * UNITS + (u0 + ec);

    // --- B fragments (atomic loads -> not rematerializable -> stay in regs) ---
    short8 bfr[4][2][3];
    #pragma unroll
    for (int ks = 0; ks < 4; ++ks) {
        const int koff = kq * 128 + ks * 32 + quad * 8;
        #pragma unroll
        for (int nq = 0; nq < 2; ++nq) {
            const size_t ub = (size_t)(u0 + nq * 16 + n16) * UNITS + koff;
            bfr[ks][nq][0] = ld_agent_b16x8(Ut1 + ub);
            bfr[ks][nq][1] = ld_agent_b16x8(Ut2 + ub);
            bfr[ks][nq][2] = ld_agent_b16x8(Ut3 + ub);
        }
    }

    const size_t HS = (size_t)64 * UNITS;            // fp32 elems per buffer
    const u64* wflag = (const u64*)(flags + (rg * 32 + kq * 4) * 8);  // 32 flags
    u32* myflag = flags + ((size_t)(rg * 32 + ug) * 8) + kq;
    const int fidx = lane & 15;

    int sb3 = 0;                                     // t % 3
    for (int t = 0; t < T_STEPS; ++t) {
        const int db3 = (sb3 == 2) ? 0 : sb3 + 1;
        const size_t sb = (size_t)sb3 * HS;
        const size_t db = (size_t)db3 * HS;
        const int tb = t & 1;

        // per-lane xW prefetch (latency hides under poll)
        const int xt = dir ? (T_STEPS - 1 - t) : t;
        const float xv = xW[(size_t)xt * (BATCH * UNITS) +
                            (size_t)eb * UNITS + (u0 + ec)];

        // ---- poll the 32 per-wave flags of the 4 source blocks ----
        const u32 tgt = (u32)t;
        for (;;) {
            u64 q = ld_agent_u64(wflag + fidx);
            int ok = ((u32)q >= tgt) && ((u32)(q >> 32) >= tgt);
            if (__all(ok)) break;
        }

        // ---- load fp32 h, split to 3 bf16 planes, MFMA (r0 scheme) ----
        f32x4 acc[2][2] = {{{0.f,0.f,0.f,0.f},{0.f,0.f,0.f,0.f}},
                           {{0.f,0.f,0.f,0.f},{0.f,0.f,0.f,0.f}}};
        #pragma unroll
        for (int ks = 0; ks < 4; ++ks) {
            const float* ap = hbuf + sb + (size_t)(R0 + n16) * UNITS +
                              kq * 128 + ks * 32 + quad * 8;
            union { u64 q[4]; float f[8]; u32 u[8]; } hv;
            hv.q[0] = ld_agent_u64((const u64*)ap);
            hv.q[1] = ld_agent_u64((const u64*)ap + 1);
            hv.q[2] = ld_agent_u64((const u64*)ap + 2);
            hv.q[3] = ld_agent_u64((const u64*)ap + 3);
            short8 a1, a2, a3;
            #pragma unroll
            for (int j = 0; j < 8; ++j) {
                float x = hv.f[j];
                u16 s1 = (u16)(hv.u[j] >> 16);          // bf16 truncation (exact residual)
                float r1 = x - bf16_f(s1);
                u16 s2 = (u16)(__float_as_uint(r1) >> 16);
                float r2 = r1 - bf16_f(s2);
                u16 s3 = (u16)(__float_as_uint(r2) >> 16);
                a1[j] = (short)s1; a2[j] = (short)s2; a3[j] = (short)s3;
            }
            #pragma unroll
            for (int nq = 0; nq < 2; ++nq) {
                acc[nq][0] = __builtin_amdgcn_mfma_f32_16x16x32_bf16(a1, bfr[ks][nq][0], acc[nq][0], 0, 0, 0);
                acc[nq][1] = __builtin_amdgcn_mfma_f32_16x16x32_bf16(a2, bfr[ks][nq][0], acc[nq][1], 0, 0, 0);
                acc[nq][0] = __builtin_amdgcn_mfma_f32_16x16x32_bf16(a1, bfr[ks][nq][1], acc[nq][0], 0, 0, 0);
                acc[nq][1] = __builtin_amdgcn_mfma_f32_16x16x32_bf16(a2, bfr[ks][nq][1], acc[nq][1], 0, 0, 0);
                acc[nq][0] = __builtin_amdgcn_mfma_f32_16x16x32_bf16(a1, bfr[ks][nq][2], acc[nq][0], 0, 0, 0);
                acc[nq][1] = __builtin_amdgcn_mfma_f32_16x16x32_bf16(a3, bfr[ks][nq][0], acc[nq][1], 0, 0, 0);
            }
        }
        f32x4 c0 = acc[0][0] + acc[0][1];
        f32x4 c1 = acc[1][0] + acc[1][1];

        // ---- publish partials (conflict-free padded layout) ----
        #pragma unroll
        for (int j = 0; j < 4; ++j) {
            redf[tb][kq][0][lane][j] = c0[j];
            redf[tb][kq][1][lane][j] = c1[j];
        }
        // the ONE barrier per step: per-wave vmcnt(0)+lgkmcnt(0) before
        // s_barrier drains this wave's state-t loads (WAR chain anchor) and
        // makes all redf[tb] writes visible.
        __syncthreads();

        // ---- all-lane reduce + activation + coalesced store + wave flag ----
        float s = 0.f;
        #pragma unroll
        for (int k2 = 0; k2 < 8; ++k2)
            s += redf[tb][k2][enq][ele][eje];
        s += xv;
        s = fminf(fmaxf(s, 0.f), CLIPV);
        st_agent_f(hbuf + db + hoff, s);
        if ((tid & 63) == 0)
            __hip_atomic_store(myflag, (u32)(t + 1), __ATOMIC_RELEASE,
                               __HIP_MEMORY_SCOPE_AGENT);
        sb3 = db3;
    }

    // ---- epilogue: out = hf + hb (state 800 lives in buffer 800%3 == 2) ----
    if (rg < 2) {
        const u32* f0 = flags + (rg * 32 + ug) * 8;          // own block (fwd rows)
        const u32* f1 = flags + ((rg + 2) * 32 + ug) * 8;    // bwd partner
        for (;;) {
            int ok = 1;
            #pragma unroll
            for (int w = 0; w < 8; ++w) {
                ok &= (ld_agent_u32(f0 + w) >= (u32)T_STEPS);
                ok &= (ld_agent_u32(f1 + w) >= (u32)T_STEPS);
            }
            if (ok) break;
        }
        const float* fin = hbuf + (size_t)(T_STEPS % 3) * HS;
        const int r = tid >> 5, c = tid & 31;
        const int b = R0 + r;
        float hf = ld_agent_f(fin + (size_t)b * UNITS + u0 + c);
        float hb = ld_agent_f(fin + (size_t)(b + 32) * UNITS + u0 + c);
        out[(size_t)b * UNITS + u0 + c] = hf + hb;
    }
}

// ---------------------------------------------------------------------------
extern "C" void kernel_launch(void* const* d_in, const int* in_sizes, int n_in,
                              void* d_out, int out_size, void* d_ws, size_t ws_size,
                              hipStream_t stream) {
    const float* inp  = (const float*)d_in[0];   // [32][800][161]
    const float* W    = (const float*)d_in[1];   // [161][1024]
    const float* U    = (const float*)d_in[2];   // [1024][1024]
    const float* bias = (const float*)d_in[3];   // [1024]
    float* out = (float*)d_out;                  // [32][1024]

    u16*   Ut1 = (u16*)d_ws;                              // 3 x 2 MB bf16 planes
    u16*   Ut2 = Ut1 + (size_t)UNITS * UNITS;
    u16*   Ut3 = Ut2 + (size_t)UNITS * UNITS;
    float* xW  = (float*)(Ut3 + (size_t)UNITS * UNITS);   // 104.9 MB
    float* hbuf = xW + (size_t)T_STEPS * BATCH * UNITS;   // 3 x 256 KB fp32
    u32*   flags = (u32*)(hbuf + (size_t)3 * 64 * UNITS); // 1024 words

    init_ws<<<64, 256, 0, stream>>>(hbuf, flags);
    u_split_t<<<dim3(32, 32), 256, 0, stream>>>(U, Ut1, Ut2, Ut3);
    xw_gemm<<<dim3(800, 4), 256, 0, stream>>>(inp, W, bias, xW);

    void* args[] = {(void*)&xW, (void*)&Ut1, (void*)&Ut2, (void*)&Ut3,
                    (void*)&hbuf, (void*)&flags, (void*)&out};
    hipLaunchCooperativeKernel((const void*)rnn_scan, dim3(128), dim3(512),
                               args, 0, stream);
}

// Round 3
// 4101.078 us; speedup vs baseline: 2.9735x; 2.9735x over previous
//
#include <hip/hip_runtime.h>
#include <hip/hip_bf16.h>

#define T_STEPS 800
#define BATCH   32
#define FEAT    161
#define UNITS   1024
#define CLIPV   20.0f

typedef __attribute__((ext_vector_type(8))) short short8;
typedef __attribute__((ext_vector_type(4))) float f32x4;
typedef unsigned short u16;
typedef unsigned int   u32;
typedef unsigned long long u64;

__device__ __forceinline__ float bf16_f(u16 u) {
    return __uint_as_float(((u32)u) << 16);
}
__device__ __forceinline__ u16 bf16_rn(float x) {
    __hip_bfloat16 b = __float2bfloat16(x);
    return *(u16*)&b;
}
__device__ __forceinline__ u64 ld_agent_u64(const u64* p) {
    return __hip_atomic_load(p, __ATOMIC_RELAXED, __HIP_MEMORY_SCOPE_AGENT);
}
__device__ __forceinline__ float ld_agent_f(const float* p) {
    return __hip_atomic_load(p, __ATOMIC_RELAXED, __HIP_MEMORY_SCOPE_AGENT);
}
// Publish via atomic-exchange RMW: performed AT the MALL (agent coherence
// point) and leaves the line resident there, unlike an agent-scope atomic
// store which writes through toward HBM without updating/allocating the MALL
// line (r0 counters: 800x256KB of h appeared in BOTH FETCH_SIZE and
// WRITE_SIZE -> every step's h exchange was a full HBM write+read RT).
__device__ __forceinline__ void xchg_agent_u32(u32* p, u32 v) {
    (void)__hip_atomic_exchange(p, v, __ATOMIC_RELAXED, __HIP_MEMORY_SCOPE_AGENT);
}
__device__ __forceinline__ void xchg_agent_f(float* p, float v) {
    xchg_agent_u32((u32*)p, __float_as_uint(v));
}
__device__ __forceinline__ short8 ld_agent_b16x8(const u16* p) {
    union { u64 q[2]; short8 v; } u;
    u.q[0] = ld_agent_u64((const u64*)p);
    u.q[1] = ld_agent_u64((const u64*)p + 1);
    return u.v;
}

// ---------------------------------------------------------------------------
// zero h double-buffer (2 x 64 x 1024 fp32) + flags
__global__ __launch_bounds__(256) void init_ws(float* hbuf, u32* flags) {
    int gid = blockIdx.x * 256 + threadIdx.x;         // 16384 threads
    for (int i = gid; i < 2 * 64 * UNITS; i += 64 * 256) hbuf[i] = 0.f;
    if (gid < 256) flags[gid] = 0u;
}

// ---------------------------------------------------------------------------
// Ut splits: U[k][u] fp32 -> Ut1/2/3[u][k] bf16 (hi/mid/lo, 24-bit total)
__global__ __launch_bounds__(256) void u_split_t(const float* __restrict__ U,
                                                 u16* __restrict__ Ut1,
                                                 u16* __restrict__ Ut2,
                                                 u16* __restrict__ Ut3) {
    __shared__ float tile[32][33];
    int bx = blockIdx.x, by = blockIdx.y;
    int lx = threadIdx.x & 31;
    int ly4 = (threadIdx.x >> 5) * 4;
    #pragma unroll
    for (int j = 0; j < 4; ++j)
        tile[ly4 + j][lx] = U[(size_t)(by * 32 + ly4 + j) * UNITS + bx * 32 + lx];
    __syncthreads();
    #pragma unroll
    for (int j = 0; j < 4; ++j) {
        float x = tile[lx][ly4 + j];
        size_t o = (size_t)(bx * 32 + ly4 + j) * UNITS + by * 32 + lx;
        u16 s1 = bf16_rn(x);  float r1 = x - bf16_f(s1);
        u16 s2 = bf16_rn(r1); float r2 = r1 - bf16_f(s2);
        u16 s3 = bf16_rn(r2);
        Ut1[o] = s1; Ut2[o] = s2; Ut3[o] = s3;
    }
}

// ---------------------------------------------------------------------------
__global__ __launch_bounds__(256) void xw_gemm(const float* __restrict__ inp,
                                               const float* __restrict__ W,
                                               const float* __restrict__ bias,
                                               float* __restrict__ xW) {
    __shared__ float xs[8 * FEAT];
    int t = blockIdx.x;
    int b0 = blockIdx.y * 8;
    int tid = threadIdx.x;

    for (int i = tid; i < 8 * FEAT; i += 256) {
        int j = i / FEAT;
        int f = i - j * FEAT;
        xs[i] = inp[((size_t)(b0 + j) * T_STEPS + t) * FEAT + f];
    }
    __syncthreads();

    float bv[4];
    #pragma unroll
    for (int c = 0; c < 4; ++c) bv[c] = bias[tid + c * 256];

    float acc[8][4];
    #pragma unroll
    for (int j = 0; j < 8; ++j)
        #pragma unroll
        for (int c = 0; c < 4; ++c) acc[j][c] = bv[c];

    for (int f = 0; f < FEAT; ++f) {
        float w0 = W[(size_t)f * UNITS + tid];
        float w1 = W[(size_t)f * UNITS + tid + 256];
        float w2 = W[(size_t)f * UNITS + tid + 512];
        float w3 = W[(size_t)f * UNITS + tid + 768];
        #pragma unroll
        for (int j = 0; j < 8; ++j) {
            float xv = xs[j * FEAT + f];
            acc[j][0] += xv * w0;
            acc[j][1] += xv * w1;
            acc[j][2] += xv * w2;
            acc[j][3] += xv * w3;
        }
    }

    #pragma unroll
    for (int j = 0; j < 8; ++j)
        #pragma unroll
        for (int c = 0; c < 4; ++c)
            xW[((size_t)t * BATCH + b0 + j) * UNITS + tid + c * 256] = acc[j][c];
}

// ---------------------------------------------------------------------------
// Dataflow MFMA scan. 128 blocks x 512 threads. (r0 structure, verbatim,
// except h/flag publishes are atomicExch RMWs -> performed at MALL, line
// stays MALL-resident, consumers' relaxed loads hit MALL instead of HBM.)
// Block (rg 0..3, ug 0..31): rows [rg*16,+16) (row = dir*32+b), cols [ug*32,+32).
// Wave kq: k-slice [kq*128,+128); its 4 source slices are written by blocks
// (rg, 4kq..4kq+3). Sync = per-writer monotone flags only — NO grid barrier:
// writer exchanges fp32 slice -> __syncthreads (drains vmcnt => RMWs performed
// at MALL) -> flag exch = t+1; reader wave polls its 4 flags (one 16B load)
// >= t. WAR-safe with 2 buffers because a writer reaching step t+1 implies
// all blocks stored step t, which implies all step-t loads are complete
// (loads precede each block's store).
// h exchanged as fp32; reader splits to 3 bf16 planes in VALU (24-bit exact).
__global__ __launch_bounds__(512) void rnn_scan(
        const float* __restrict__ xW,
        const u16* __restrict__ Ut1, const u16* __restrict__ Ut2,
        const u16* __restrict__ Ut3,
        float* __restrict__ hbuf, u32* __restrict__ flags,
        float* __restrict__ out) {
    __shared__ f32x4 red[14][64];   // 14 KB cross-wave C partials

    const int tid  = threadIdx.x;
    const int bk   = blockIdx.x;
    const int lane = tid & 63;
    const int kq   = tid >> 6;       // 0..7
    const int quad = lane >> 4;      // 0..3
    const int n16  = lane & 15;
    const int rg   = bk & 3;
    const int ug   = bk >> 2;
    const int R0   = rg * 16;
    const int u0   = ug * 32;
    const int dir  = rg >> 1;

    // --- B fragments (atomic loads -> not rematerializable -> stay in regs) ---
    short8 bfr[4][2][3];
    #pragma unroll
    for (int ks = 0; ks < 4; ++ks) {
        const int koff = kq * 128 + ks * 32 + quad * 8;
        #pragma unroll
        for (int nq = 0; nq < 2; ++nq) {
            const size_t ub = (size_t)(u0 + nq * 16 + n16) * UNITS + koff;
            bfr[ks][nq][0] = ld_agent_b16x8(Ut1 + ub);
            bfr[ks][nq][1] = ld_agent_b16x8(Ut2 + ub);
            bfr[ks][nq][2] = ld_agent_b16x8(Ut3 + ub);
        }
    }

    const size_t HS = (size_t)64 * UNITS;            // fp32 elems per buffer
    u32* myflag = flags + rg * 32 + ug;
    const u64* srcflag = (const u64*)(flags + rg * 32 + kq * 4);

    for (int t = 0; t < T_STEPS; ++t) {
        const size_t sb = (size_t)(t & 1) * HS;
        const size_t db = sb ^ HS;

        // xW prefetch (combining wave only)
        float xp[2][4];
        if (kq == 0) {
            const int xt = dir ? (T_STEPS - 1 - t) : t;
            #pragma unroll
            for (int nq = 0; nq < 2; ++nq)
                #pragma unroll
                for (int j = 0; j < 4; ++j) {
                    const int b = (R0 + quad * 4 + j) & 31;
                    xp[nq][j] = xW[(size_t)xt * (BATCH * UNITS) +
                                   (size_t)b * UNITS + u0 + nq * 16 + n16];
                }
        }

        // ---- wait for this wave's 4 source slices (one 16B poll load) ----
        const u32 tgt = (u32)t;
        for (;;) {
            u64 qa = ld_agent_u64(srcflag);
            u64 qb = ld_agent_u64(srcflag + 1);
            u32 f0 = (u32)qa, f1 = (u32)(qa >> 32);
            u32 f2 = (u32)qb, f3 = (u32)(qb >> 32);
            if (f0 >= tgt && f1 >= tgt && f2 >= tgt && f3 >= tgt) break;
        }

        // ---- load fp32 h, split to 3 bf16 planes, MFMA ----
        f32x4 acc[2][2] = {{{0.f,0.f,0.f,0.f},{0.f,0.f,0.f,0.f}},
                           {{0.f,0.f,0.f,0.f},{0.f,0.f,0.f,0.f}}};
        #pragma unroll
        for (int ks = 0; ks < 4; ++ks) {
            const float* ap = hbuf + sb + (size_t)(R0 + n16) * UNITS +
                              kq * 128 + ks * 32 + quad * 8;
            union { u64 q[4]; float f[8]; u32 u[8]; } hv;
            hv.q[0] = ld_agent_u64((const u64*)ap);
            hv.q[1] = ld_agent_u64((const u64*)ap + 1);
            hv.q[2] = ld_agent_u64((const u64*)ap + 2);
            hv.q[3] = ld_agent_u64((const u64*)ap + 3);
            short8 a1, a2, a3;
            #pragma unroll
            for (int j = 0; j < 8; ++j) {
                float x = hv.f[j];
                u16 s1 = (u16)(hv.u[j] >> 16);          // bf16 truncation (exact residual)
                float r1 = x - bf16_f(s1);
                u16 s2 = (u16)(__float_as_uint(r1) >> 16);
                float r2 = r1 - bf16_f(s2);
                u16 s3 = (u16)(__float_as_uint(r2) >> 16);
                a1[j] = (short)s1; a2[j] = (short)s2; a3[j] = (short)s3;
            }
            #pragma unroll
            for (int nq = 0; nq < 2; ++nq) {
                acc[nq][0] = __builtin_amdgcn_mfma_f32_16x16x32_bf16(a1, bfr[ks][nq][0], acc[nq][0], 0, 0, 0);
                acc[nq][1] = __builtin_amdgcn_mfma_f32_16x16x32_bf16(a2, bfr[ks][nq][0], acc[nq][1], 0, 0, 0);
                acc[nq][0] = __builtin_amdgcn_mfma_f32_16x16x32_bf16(a1, bfr[ks][nq][1], acc[nq][0], 0, 0, 0);
                acc[nq][1] = __builtin_amdgcn_mfma_f32_16x16x32_bf16(a2, bfr[ks][nq][1], acc[nq][1], 0, 0, 0);
                acc[nq][0] = __builtin_amdgcn_mfma_f32_16x16x32_bf16(a1, bfr[ks][nq][2], acc[nq][0], 0, 0, 0);
                acc[nq][1] = __builtin_amdgcn_mfma_f32_16x16x32_bf16(a3, bfr[ks][nq][0], acc[nq][1], 0, 0, 0);
            }
        }
        f32x4 c0 = acc[0][0] + acc[0][1];
        f32x4 c1 = acc[1][0] + acc[1][1];

        // ---- cross-wave k-reduction through LDS ----
        if (kq) {
            red[(kq - 1) * 2 + 0][lane] = c0;
            red[(kq - 1) * 2 + 1][lane] = c1;
        }
        __syncthreads();
        if (kq == 0) {
            #pragma unroll
            for (int w = 0; w < 7; ++w) {
                c0 += red[w * 2 + 0][lane];
                c1 += red[w * 2 + 1][lane];
            }
            float* hdst = hbuf + db;
            #pragma unroll
            for (int nq = 0; nq < 2; ++nq)
                #pragma unroll
                for (int j = 0; j < 4; ++j) {
                    float a = (nq ? c1[j] : c0[j]) + xp[nq][j];
                    a = fminf(fmaxf(a, 0.f), CLIPV);
                    xchg_agent_f(hdst + (size_t)(R0 + quad * 4 + j) * UNITS +
                                 u0 + nq * 16 + n16, a);
                }
        }
        // barrier: (a) protects red[] for next step, (b) compiler emits
        // s_waitcnt vmcnt(0) per wave before s_barrier -> kq0's h exchanges
        // are PERFORMED at the MALL before the flag is published.
        __syncthreads();
        if (tid == 0) xchg_agent_u32(myflag, (u32)(t + 1));
    }

    // ---- epilogue: out = hf + hb (final state in buffer 0; 800 even) ----
    if (rg < 2) {
        // own fwd slice is done (this block wrote it); wait for bwd partner
        const u32* bwd = flags + (rg + 2) * 32 + ug;
        while (__hip_atomic_load(bwd, __ATOMIC_RELAXED,
                                 __HIP_MEMORY_SCOPE_AGENT) < (u32)T_STEPS) {}
        const int r = tid >> 5, c = tid & 31;
        const int b = R0 + r;
        float hf = ld_agent_f(hbuf + (size_t)b * UNITS + u0 + c);
        float hb = ld_agent_f(hbuf + (size_t)(b + 32) * UNITS + u0 + c);
        out[(size_t)b * UNITS + u0 + c] = hf + hb;
    }
}

// ---------------------------------------------------------------------------
extern "C" void kernel_launch(void* const* d_in, const int* in_sizes, int n_in,
                              void* d_out, int out_size, void* d_ws, size_t ws_size,
                              hipStream_t stream) {
    const float* inp  = (const float*)d_in[0];   // [32][800][161]
    const float* W    = (const float*)d_in[1];   // [161][1024]
    const float* U    = (const float*)d_in[2];   // [1024][1024]
    const float* bias = (const float*)d_in[3];   // [1024]
    float* out = (float*)d_out;                  // [32][1024]

    u16*   Ut1 = (u16*)d_ws;                              // 3 x 2 MB bf16 planes
    u16*   Ut2 = Ut1 + (size_t)UNITS * UNITS;
    u16*   Ut3 = Ut2 + (size_t)UNITS * UNITS;
    float* xW  = (float*)(Ut3 + (size_t)UNITS * UNITS);   // 104.9 MB
    float* hbuf = xW + (size_t)T_STEPS * BATCH * UNITS;   // 2 x 256 KB fp32
    u32*   flags = (u32*)(hbuf + (size_t)2 * 64 * UNITS); // 256 words

    init_ws<<<64, 256, 0, stream>>>(hbuf, flags);
    u_split_t<<<dim3(32, 32), 256, 0, stream>>>(U, Ut1, Ut2, Ut3);
    xw_gemm<<<dim3(800, 4), 256, 0, stream>>>(inp, W, bias, xW);

    void* args[] = {(void*)&xW, (void*)&Ut1, (void*)&Ut2, (void*)&Ut3,
                    (void*)&hbuf, (void*)&flags, (void*)&out};
    hipLaunchCooperativeKernel((const void*)rnn_scan, dim3(128), dim3(512),
                               args, 0, stream);
}